// Round 7
// baseline (719.413 us; speedup 1.0000x reference)
//
#include <hip/hip_runtime.h>
#include <hip/hip_bf16.h>

// Problem: L=4 B=4 N=2048 D=512 H=8 HD=64. Inputs/outputs FP32.
// Weights transposed+cast to bf16 once; bf16 MFMA, fp32 accumulate; fp32
// residual stream. scale = 512^-0.5 (D**-0.5 per ref).
// Attention v5 (2x2 kv/q split) — unchanged from round 6.
// GEMMs: QKV = 128x128 BK=32 (3 blocks/CU regime). O-proj/FFN = 128x128
// BK=64 double-buffered (grid 256 = 1 block/CU, 64 KB LDS, 8 barriers).

typedef __bf16 bf16x8 __attribute__((ext_vector_type(8)));
typedef short short4v __attribute__((ext_vector_type(4)));
typedef float f32x4 __attribute__((ext_vector_type(4)));
typedef unsigned int u32x4 __attribute__((ext_vector_type(4)));
typedef unsigned int u32x2 __attribute__((ext_vector_type(2)));
typedef unsigned short u16;

__device__ __forceinline__ u16 f2b(float f) {  // RNE (values are finite)
  unsigned int u; __builtin_memcpy(&u, &f, 4);
  u += 0x7fffu + ((u >> 16) & 1u);
  return (u16)(u >> 16);
}
__device__ __forceinline__ bf16x8 ld8(const u16* p) {
  u32x4 t = *(const u32x4*)p;
  bf16x8 r; __builtin_memcpy(&r, &t, 16); return r;
}
__device__ __forceinline__ short4v ld4(const u16* p) {
  u32x2 t = *(const u32x2*)p;
  short4v r; __builtin_memcpy(&r, &t, 8); return r;
}
__device__ __forceinline__ unsigned pkhi(float a, float b) {
  unsigned ua, ub; __builtin_memcpy(&ua, &a, 4); __builtin_memcpy(&ub, &b, 4);
  return __builtin_amdgcn_perm(ua, ub, 0x07060302u);
}

#define GLL(gp, lp) __builtin_amdgcn_global_load_lds( \
    (const __attribute__((address_space(1))) void*)(gp), \
    (__attribute__((address_space(3))) void*)(lp), 16, 0, 0)

__device__ __forceinline__ int swz(int r) { return (r + (r >> 2)) & 3; }

// ---------------------------------------------------------------------------
// Weight transpose + fp32->bf16 cast: out[l][n][k] = bf16(in[l][k][n])
// ---------------------------------------------------------------------------
__global__ __launch_bounds__(256) void tr_k(const float* __restrict__ in,
                                            u16* __restrict__ out,
                                            int out_l_stride, int out_off) {
  __shared__ float t[32][33];
  int tx = threadIdx.x, ty = threadIdx.y;
  int l = blockIdx.z;
  int k0 = blockIdx.y * 32, n0 = blockIdx.x * 32;
  const float* ip = in + l * 262144;
#pragma unroll
  for (int i = 0; i < 4; i++)
    t[ty + i * 8][tx] = ip[(k0 + ty + i * 8) * 512 + n0 + tx];
  __syncthreads();
  u16* op = out + l * out_l_stride + out_off;
#pragma unroll
  for (int i = 0; i < 4; i++)
    op[(n0 + ty + i * 8) * 512 + k0 + tx] = f2b(t[tx][ty + i * 8]);
}

// ---------------------------------------------------------------------------
__global__ __launch_bounds__(256) void copy_k(const float* __restrict__ src,
                                              float* __restrict__ dst) {
  int i = (blockIdx.x * 256 + threadIdx.x) * 4;
  *(float4*)&dst[i] = *(const float4*)&src[i];
}

// ---------------------------------------------------------------------------
// LayerNorm: one wave per token (D=512, 8 elems/lane), fp32 in, bf16 out
// ---------------------------------------------------------------------------
__global__ __launch_bounds__(256) void ln_k(const float* __restrict__ h,
                                            const float* __restrict__ gg,
                                            const float* __restrict__ bb,
                                            u16* __restrict__ y) {
  int tid = threadIdx.x, wave = tid >> 6, lane = tid & 63;
  int tok = blockIdx.x * 4 + wave;
  const float* hp = h + tok * 512 + lane * 8;
  float x[8];
  *(float4*)&x[0] = *(const float4*)hp;
  *(float4*)&x[4] = *(const float4*)(hp + 4);
  float s = 0.f, ss = 0.f;
#pragma unroll
  for (int i = 0; i < 8; i++) { s += x[i]; ss += x[i] * x[i]; }
#pragma unroll
  for (int off = 1; off < 64; off <<= 1) {
    s += __shfl_xor(s, off, 64);
    ss += __shfl_xor(ss, off, 64);
  }
  float mean = s * (1.0f / 512.0f);
  float var = ss * (1.0f / 512.0f) - mean * mean;
  float rstd = rsqrtf(var + 1e-5f);
  u32x4 ov;
#pragma unroll
  for (int i = 0; i < 4; i++) {
    int d0 = lane * 8 + i * 2;
    float y0 = (x[i * 2]     - mean) * rstd * gg[d0]     + bb[d0];
    float y1 = (x[i * 2 + 1] - mean) * rstd * gg[d0 + 1] + bb[d0 + 1];
    ov[i] = (unsigned)f2b(y0) | ((unsigned)f2b(y1) << 16);
  }
  *(u32x4*)&y[tok * 512 + lane * 8] = ov;
}

// ---------------------------------------------------------------------------
// GEMM2: 128x128, BK=64, double-buffered. C[8192][512] = A * Bt^T.
// grid (4,64) = 256 blocks = 1/CU; 64 KB LDS; 8 barrier rounds.
// LDS rows of 64 elems = 8 chunks of 16B; chunk j of row r holds source
// chunk j^(r&7) (XOR swizzle, staged with sgc = (lane&7)^(lane>>3)).
// Epilogues: RES (h += gemm + bias, optional fp32 out copy), GELU.
// ---------------------------------------------------------------------------
enum { EPI_RES = 1, EPI_GELU = 2 };

template <int EPI>
__global__ __launch_bounds__(256, 2) void gemm2_k(
    const u16* __restrict__ A, const u16* __restrict__ Bt,
    const float* __restrict__ bias, u16* __restrict__ out0,
    float* __restrict__ hres, float* __restrict__ fout) {
  __shared__ __align__(16) u16 As[2][128 * 64];  // 2 x 16 KB
  __shared__ __align__(16) u16 Bs[2][128 * 64];  // 2 x 16 KB
  const int tid = threadIdx.x;
  const int wave = tid >> 6, lane = tid & 63;
  const int quad = lane >> 4, l16 = lane & 15;
  const int swl = l16 & 7;
  const int wm = wave >> 1, wn = wave & 1;
  const int m0 = blockIdx.y * 128;
  const int n0 = blockIdx.x * 128;

  f32x4 acc[4][4];
#pragma unroll
  for (int i = 0; i < 4; i++)
#pragma unroll
    for (int j = 0; j < 4; j++) acc[i][j] = f32x4{0.f, 0.f, 0.f, 0.f};

  // staging: thread covers rows rnd*32 + wave*8 + srow, rnd=0..3
  const int srow = lane >> 3, sgc = (lane & 7) ^ srow;
  // frag bases (kt-invariant, element index into 128x64 tile)
  int kbA[2], kbB[2];
#pragma unroll
  for (int kk = 0; kk < 2; ++kk) {
    kbA[kk] = (wm * 64 + l16) * 64 + ((kk * 4 + quad) ^ swl) * 8;
    kbB[kk] = (wn * 64 + l16) * 64 + ((kk * 4 + quad) ^ swl) * 8;
  }

  // prologue: stage kt=0 into buf 0
#pragma unroll
  for (int rnd = 0; rnd < 4; ++rnd) {
    int row = rnd * 32 + wave * 8 + srow;
    GLL(A + (size_t)(m0 + row) * 512 + sgc * 8, &As[0][(rnd * 256 + wave * 64) * 8]);
    GLL(Bt + (size_t)(n0 + row) * 512 + sgc * 8, &Bs[0][(rnd * 256 + wave * 64) * 8]);
  }

#pragma unroll 2
  for (int kt = 0; kt < 8; ++kt) {
    __syncthreads();
    const u16* AsB = As[kt & 1];
    const u16* BsB = Bs[kt & 1];
    if (kt + 1 < 8) {
      u16* AsN = (u16*)As[(kt & 1) ^ 1];
      u16* BsN = (u16*)Bs[(kt & 1) ^ 1];
      const int k1 = (kt + 1) * 64;
#pragma unroll
      for (int rnd = 0; rnd < 4; ++rnd) {
        int row = rnd * 32 + wave * 8 + srow;
        GLL(A + (size_t)(m0 + row) * 512 + k1 + sgc * 8, AsN + (rnd * 256 + wave * 64) * 8);
        GLL(Bt + (size_t)(n0 + row) * 512 + k1 + sgc * 8, BsN + (rnd * 256 + wave * 64) * 8);
      }
    }

#pragma unroll
    for (int kk = 0; kk < 2; ++kk) {
      bf16x8 af[4], bf_[4];
#pragma unroll
      for (int mi = 0; mi < 4; ++mi) af[mi] = ld8(AsB + kbA[kk] + mi * 1024);
#pragma unroll
      for (int ni = 0; ni < 4; ++ni) bf_[ni] = ld8(BsB + kbB[kk] + ni * 1024);
#pragma unroll
      for (int mi = 0; mi < 4; ++mi)
#pragma unroll
        for (int ni = 0; ni < 4; ++ni)
          acc[mi][ni] = __builtin_amdgcn_mfma_f32_16x16x32_bf16(
              af[mi], bf_[ni], acc[mi][ni], 0, 0, 0);
    }
  }

  // Epilogue. C layout: row = quad*4+reg, col = l16.
  const int mb = m0 + wm * 64, nb = n0 + wn * 64;
#pragma unroll
  for (int mi = 0; mi < 4; ++mi) {
#pragma unroll
    for (int ni = 0; ni < 4; ++ni) {
      f32x4 a = acc[mi][ni];
      int r0 = mb + mi * 16 + quad * 4;
      int c = nb + ni * 16 + l16;
      if constexpr (EPI == EPI_RES) {
        float bi = bias[c];
#pragma unroll
        for (int g = 0; g < 4; ++g) {
          float v = hres[(size_t)(r0 + g) * 512 + c] + a[g] + bi;
          hres[(size_t)(r0 + g) * 512 + c] = v;
          if (fout) fout[(size_t)(r0 + g) * 512 + c] = v;
        }
      } else {  // GELU
        float bi = bias[c];
#pragma unroll
        for (int g = 0; g < 4; ++g) {
          float t = a[g] + bi;
          float gl = 0.5f * t * (1.0f + erff(t * 0.70710678118654752f));
          out0[(size_t)(r0 + g) * 512 + c] = f2b(gl);
        }
      }
    }
  }
}

// ---------------------------------------------------------------------------
// QKV GEMM 128x128 (BK=32): C[8192][1536] = A * Wqkv^T. Epilogue splits
// Q (pre-scaled by 512^-0.5*log2e), K, and V (transposed to vt[b,h,d,n]).
// ---------------------------------------------------------------------------
__global__ __launch_bounds__(256, 4) void gemm_qkv_k(
    const u16* __restrict__ A, const u16* __restrict__ Bt,
    u16* __restrict__ outq, u16* __restrict__ outk, u16* __restrict__ outvt) {
  __shared__ __align__(16) u16 As[128 * 32];
  __shared__ __align__(16) u16 Bs[128 * 32];
  const int tid = threadIdx.x;
  const int wave = tid >> 6, lane = tid & 63;
  const int quad = lane >> 4, l16 = lane & 15;
  const int wm = wave >> 1, wn = wave & 1;
  const int m0 = blockIdx.y * 128;
  const int n0 = blockIdx.x * 128;

  f32x4 acc[4][4];
#pragma unroll
  for (int i = 0; i < 4; i++)
#pragma unroll
    for (int j = 0; j < 4; j++) acc[i][j] = f32x4{0.f, 0.f, 0.f, 0.f};

  const int sA0 = wave * 64 + lane;

  for (int kt = 0; kt < 16; ++kt) {
    const int k0 = kt * 32;
    __syncthreads();
#pragma unroll
    for (int rnd = 0; rnd < 2; ++rnd) {
      int s = rnd * 256 + sA0;
      int row = s >> 2, c = s & 3;
      int cg = c ^ swz(row);
      GLL(A + (m0 + row) * 512 + k0 + cg * 8, &As[(rnd * 256 + wave * 64) * 8]);
      GLL(Bt + (n0 + row) * 512 + k0 + cg * 8, &Bs[(rnd * 256 + wave * 64) * 8]);
    }
    __syncthreads();

    bf16x8 af[4], bf_[4];
#pragma unroll
    for (int mi = 0; mi < 4; ++mi) {
      int r = wm * 64 + mi * 16 + l16;
      af[mi] = ld8(&As[r * 32 + (quad ^ swz(r)) * 8]);
    }
#pragma unroll
    for (int ni = 0; ni < 4; ++ni) {
      int r = wn * 64 + ni * 16 + l16;
      bf_[ni] = ld8(&Bs[r * 32 + (quad ^ swz(r)) * 8]);
    }
#pragma unroll
    for (int mi = 0; mi < 4; ++mi)
#pragma unroll
      for (int ni = 0; ni < 4; ++ni)
        acc[mi][ni] = __builtin_amdgcn_mfma_f32_16x16x32_bf16(
            af[mi], bf_[ni], acc[mi][ni], 0, 0, 0);
  }

  const int mb = m0 + wm * 64, nb = n0 + wn * 64;
#pragma unroll
  for (int mi = 0; mi < 4; ++mi) {
#pragma unroll
    for (int ni = 0; ni < 4; ++ni) {
      f32x4 a = acc[mi][ni];
      int r0 = mb + mi * 16 + quad * 4;
      int c = nb + ni * 16 + l16;
      if (c < 512) {
        const float C2 = 0.06375871506958306f;  // 512^-0.5 * log2(e)
#pragma unroll
        for (int g = 0; g < 4; ++g) outq[(r0 + g) * 512 + c] = f2b(a[g] * C2);
      } else if (c < 1024) {
#pragma unroll
        for (int g = 0; g < 4; ++g) outk[(r0 + g) * 512 + (c - 512)] = f2b(a[g]);
      } else {
        int cv = c - 1024, hh = cv >> 6, dd = cv & 63;
        int bb = r0 >> 11, nt = r0 & 2047;
        u32x2 pk;
        pk[0] = (unsigned)f2b(a[0]) | ((unsigned)f2b(a[1]) << 16);
        pk[1] = (unsigned)f2b(a[2]) | ((unsigned)f2b(a[3]) << 16);
        *(u32x2*)&outvt[((bb * 8 + hh) * 64 + dd) * 2048 + nt] = pk;
      }
    }
  }
}

// ---------------------------------------------------------------------------
// Flash attention v5 (2x2 split) — unchanged from round 6.
// ---------------------------------------------------------------------------
__global__ __launch_bounds__(256, 4) void attn_k(const u16* __restrict__ q,
                                                 const u16* __restrict__ k,
                                                 const u16* __restrict__ vt,
                                                 u16* __restrict__ o) {
  __shared__ __align__(16) u16 Ks[2][64 * 64];   // 16 KB
  __shared__ __align__(16) u16 Vs[2][64 * 64];   // 16 KB
  __shared__ float Lr[4][32];                    // 512 B
  const int tid = threadIdx.x, wave = tid >> 6, lane = tid & 63;
  const int quad = lane >> 4, l16 = lane & 15;
  const int qh = quad >> 1, ql = quad & 1;
  const int swl = l16 & 7;
  const int qh2 = wave & 1, kvs = wave >> 1;
  const int bh = blockIdx.y, b = bh >> 3, h = bh & 7;
  const int qt0 = blockIdx.x * 64;

  const u16* qpb = q + (size_t)(b * 2048 + qt0 + qh2 * 32) * 512 + h * 64;
  bf16x8 aq[2][2];
#pragma unroll
  for (int qt = 0; qt < 2; ++qt) {
    const u16* qp = qpb + (size_t)(qt * 16 + l16) * 512;
    aq[qt][0] = ld8(qp + quad * 8);
    aq[qt][1] = ld8(qp + 32 + quad * 8);
  }

  const u16* kp = k + (size_t)b * 2048 * 512 + h * 64;
  const u16* vp = vt + (size_t)bh * 64 * 2048;

  const int srow = lane >> 3, schk = lane & 7, sgc = schk ^ srow;
  const int krow0 = wave * 8 + srow;
  const size_t kgl0 = (size_t)krow0 * 512 + sgc * 8;
  const size_t kgl1 = (size_t)(krow0 + 32) * 512 + sgc * 8;
  const size_t vgl0 = (size_t)krow0 * 2048 + sgc * 8;
  const size_t vgl1 = (size_t)(krow0 + 32) * 2048 + sgc * 8;

  int kb[2][2];
#pragma unroll
  for (int t = 0; t < 2; ++t) {
    kb[t][0] = (kvs * 32 + t * 16 + l16) * 64 + ((quad)     ^ swl) * 8;
    kb[t][1] = (kvs * 32 + t * 16 + l16) * 64 + ((4 + quad) ^ swl) * 8;
  }
  int vb[2];
#pragma unroll
  for (int t = 0; t < 2; ++t)
    vb[t] = l16 * 64 + ((kvs * 4 + t * 2 + qh) ^ swl) * 8 + ql * 4;

  f32x4 oacc[4][2];
#pragma unroll
  for (int i = 0; i < 4; i++)
#pragma unroll
    for (int j = 0; j < 2; j++) oacc[i][j] = f32x4{0.f, 0.f, 0.f, 0.f};
  float ls[2] = {0.f, 0.f};

  GLL(kp + kgl0, &Ks[0][(wave * 8) * 64]);
  GLL(kp + kgl1, &Ks[0][(32 + wave * 8) * 64]);
  GLL(vp + vgl0, &Vs[0][(wave * 8) * 64]);
  GLL(vp + vgl1, &Vs[0][(32 + wave * 8) * 64]);

#pragma unroll 2
  for (int kt = 0; kt < 32; ++kt) {
    __syncthreads();
    const u16* KsB = Ks[kt & 1];
    const u16* VsB = Vs[kt & 1];
    if (kt + 1 < 32) {
      u16* KsN = (u16*)Ks[(kt & 1) ^ 1];
      u16* VsN = (u16*)Vs[(kt & 1) ^ 1];
      const u16* kpn = kp + (size_t)(kt + 1) * 32768;
      const u16* vpn = vp + (size_t)(kt + 1) * 64;
      GLL(kpn + kgl0, KsN + (wave * 8) * 64);
      GLL(kpn + kgl1, KsN + (32 + wave * 8) * 64);
      GLL(vpn + vgl0, VsN + (wave * 8) * 64);
      GLL(vpn + vgl1, VsN + (32 + wave * 8) * 64);
    }

    short4v pp[2][2];
#pragma unroll
    for (int t = 0; t < 2; ++t) {
      bf16x8 kf0 = ld8(KsB + kb[t][0]);
      bf16x8 kf1 = ld8(KsB + kb[t][1]);
#pragma unroll
      for (int qt = 0; qt < 2; ++qt) {
        f32x4 sa = f32x4{0.f, 0.f, 0.f, 0.f};
        sa = __builtin_amdgcn_mfma_f32_16x16x32_bf16(kf0, aq[qt][0], sa, 0, 0, 0);
        sa = __builtin_amdgcn_mfma_f32_16x16x32_bf16(kf1, aq[qt][1], sa, 0, 0, 0);
        float p0 = __builtin_amdgcn_exp2f(sa[0]);
        float p1 = __builtin_amdgcn_exp2f(sa[1]);
        float p2 = __builtin_amdgcn_exp2f(sa[2]);
        float p3 = __builtin_amdgcn_exp2f(sa[3]);
        ls[qt] += (p0 + p1) + (p2 + p3);
        u32x2 pk; pk[0] = pkhi(p1, p0); pk[1] = pkhi(p3, p2);
        __builtin_memcpy(&pp[t][qt], &pk, 8);
      }
    }

#pragma unroll
    for (int dt = 0; dt < 4; ++dt)
#pragma unroll
      for (int t = 0; t < 2; ++t) {
        short4v av = ld4(VsB + vb[t] + dt * 1024);
#pragma unroll
        for (int qt = 0; qt < 2; ++qt)
          oacc[dt][qt] = __builtin_amdgcn_mfma_f32_16x16x16bf16_1k(
              av, pp[t][qt], oacc[dt][qt], 0, 0, 0);
      }
  }

#pragma unroll
  for (int qt = 0; qt < 2; ++qt) {
    ls[qt] += __shfl_xor(ls[qt], 16, 64);
    ls[qt] += __shfl_xor(ls[qt], 32, 64);
  }
  if (quad == 0) {
#pragma unroll
    for (int qt = 0; qt < 2; ++qt) Lr[wave][qt * 16 + l16] = ls[qt];
  }
  __syncthreads();

  float* R = (float*)&Ks[0][0];
  const int l7 = lane & 7;
  if (wave >= 2) {
    float* Rw = R + (wave - 2) * 2048;
#pragma unroll
    for (int dt = 0; dt < 4; ++dt)
#pragma unroll
      for (int qt = 0; qt < 2; ++qt) {
        int s = (dt * 2 + qt) ^ l7;
        *(f32x4*)&Rw[lane * 32 + s * 4] = oacc[dt][qt];
      }
  }
  __syncthreads();
  if (wave < 2) {
    float* Rw = R + wave * 2048;
    float inv[2];
#pragma unroll
    for (int qt = 0; qt < 2; ++qt)
      inv[qt] = 1.0f / (Lr[wave][qt * 16 + l16] + Lr[wave + 2][qt * 16 + l16]);
#pragma unroll
    for (int dt = 0; dt < 4; ++dt)
#pragma unroll
      for (int qt = 0; qt < 2; ++qt) {
        int s = (dt * 2 + qt) ^ l7;
        f32x4 v = *(f32x4*)&Rw[lane * 32 + s * 4];
        float i4 = inv[qt];
        float o0 = (oacc[dt][qt][0] + v[0]) * i4;
        float o1 = (oacc[dt][qt][1] + v[1]) * i4;
        float o2 = (oacc[dt][qt][2] + v[2]) * i4;
        float o3 = (oacc[dt][qt][3] + v[3]) * i4;
        u16* op = o + (size_t)(b * 2048 + qt0 + wave * 32 + qt * 16 + l16) * 512 +
                  h * 64 + dt * 16 + quad * 4;
        u32x2 pk;
        pk[0] = (unsigned)f2b(o0) | ((unsigned)f2b(o1) << 16);
        pk[1] = (unsigned)f2b(o2) | ((unsigned)f2b(o3) << 16);
        *(u32x2*)op = pk;
      }
  }
}

// ---------------------------------------------------------------------------
extern "C" void kernel_launch(void* const* d_in, const int* in_sizes, int n_in,
                              void* d_out, int out_size, void* d_ws,
                              size_t ws_size, hipStream_t stream) {
  const float* x   = (const float*)d_in[0];
  const float* Wq  = (const float*)d_in[1];
  const float* Wk  = (const float*)d_in[2];
  const float* Wv  = (const float*)d_in[3];
  const float* Wo  = (const float*)d_in[4];
  const float* bo  = (const float*)d_in[5];
  const float* g1  = (const float*)d_in[6];
  const float* bg1 = (const float*)d_in[7];
  const float* W1  = (const float*)d_in[8];
  const float* b1  = (const float*)d_in[9];
  const float* W2  = (const float*)d_in[10];
  const float* b2  = (const float*)d_in[11];
  const float* g2  = (const float*)d_in[12];
  const float* bg2 = (const float*)d_in[13];

  char* ws = (char*)d_ws;
  float* h    = (float*)ws;                        // 16 MB fp32 residual
  u16* yb     = (u16*)(ws + (16ll << 20));         // 8 MB LN output (bf16)
  u16* qb     = (u16*)(ws + (24ll << 20));         // 8 MB q / ffn-intermediate
  u16* kb     = (u16*)(ws + (32ll << 20));         // 8 MB k
  u16* vtb    = (u16*)(ws + (40ll << 20));         // 8 MB v transposed [b,h,d,n]
  u16* ob     = (u16*)(ws + (48ll << 20));         // 8 MB attn out
  u16* wtqkv  = (u16*)(ws + (56ll << 20));         // 6 MB [l][1536][512] bf16
  u16* wto    = (u16*)(ws + (62ll << 20));         // 2 MB
  u16* wt1    = (u16*)(ws + (64ll << 20));         // 2 MB
  u16* wt2    = (u16*)(ws + (66ll << 20));         // 2 MB  (total 68 MB)

  dim3 tb(32, 8), tg(16, 16, 4);
  tr_k<<<tg, tb, 0, stream>>>(Wq, wtqkv, 1536 * 512, 0);
  tr_k<<<tg, tb, 0, stream>>>(Wk, wtqkv, 1536 * 512, 512 * 512);
  tr_k<<<tg, tb, 0, stream>>>(Wv, wtqkv, 1536 * 512, 1024 * 512);
  tr_k<<<tg, tb, 0, stream>>>(Wo, wto, 512 * 512, 0);
  tr_k<<<tg, tb, 0, stream>>>(W1, wt1, 512 * 512, 0);
  tr_k<<<tg, tb, 0, stream>>>(W2, wt2, 512 * 512, 0);
  copy_k<<<4096, 256, 0, stream>>>(x, h);

  for (int l = 0; l < 4; ++l) {
    ln_k<<<2048, 256, 0, stream>>>(h, g1 + l * 512, bg1 + l * 512, yb);
    gemm_qkv_k<<<dim3(12, 64), 256, 0, stream>>>(
        yb, wtqkv + l * 1536 * 512, qb, kb, vtb);
    attn_k<<<dim3(32, 32), 256, 0, stream>>>(qb, kb, vtb, ob);
    gemm2_k<EPI_RES><<<dim3(4, 64), 256, 0, stream>>>(
        ob, wto + l * 262144, bo + l * 512, nullptr, h, nullptr);
    ln_k<<<2048, 256, 0, stream>>>(h, g2 + l * 512, bg2 + l * 512, yb);
    gemm2_k<EPI_GELU><<<dim3(4, 64), 256, 0, stream>>>(
        yb, wt1 + l * 262144, b1 + l * 512, qb, nullptr, nullptr);
    gemm2_k<EPI_RES><<<dim3(4, 64), 256, 0, stream>>>(
        qb, wt2 + l * 262144, b2 + l * 512, nullptr, h,
        (l == 3) ? (float*)d_out : nullptr);
  }
}

// Round 8
// 621.878 us; speedup vs baseline: 1.1568x; 1.1568x over previous
//
#include <hip/hip_runtime.h>
#include <hip/hip_bf16.h>

// Problem: L=4 B=4 N=2048 D=512 H=8 HD=64. Inputs/outputs FP32.
// Weights transposed+cast to bf16 once; bf16 MFMA, fp32 accumulate; fp32
// residual stream. scale = 512^-0.5 (D**-0.5 per ref).
// Round 8: XCD-pinned grids (fast dim chooses XCD: attn x=bh, gemms x=m),
// gemm2 = 64x128 BK=64 dbuf at 2 blocks/CU, copy_k eliminated (layer-0
// reads x directly), 6 transposes fused into one launch.

typedef __bf16 bf16x8 __attribute__((ext_vector_type(8)));
typedef short short4v __attribute__((ext_vector_type(4)));
typedef float f32x4 __attribute__((ext_vector_type(4)));
typedef unsigned int u32x4 __attribute__((ext_vector_type(4)));
typedef unsigned int u32x2 __attribute__((ext_vector_type(2)));
typedef unsigned short u16;

__device__ __forceinline__ u16 f2b(float f) {  // RNE (values are finite)
  unsigned int u; __builtin_memcpy(&u, &f, 4);
  u += 0x7fffu + ((u >> 16) & 1u);
  return (u16)(u >> 16);
}
__device__ __forceinline__ bf16x8 ld8(const u16* p) {
  u32x4 t = *(const u32x4*)p;
  bf16x8 r; __builtin_memcpy(&r, &t, 16); return r;
}
__device__ __forceinline__ short4v ld4(const u16* p) {
  u32x2 t = *(const u32x2*)p;
  short4v r; __builtin_memcpy(&r, &t, 8); return r;
}
__device__ __forceinline__ unsigned pkhi(float a, float b) {
  unsigned ua, ub; __builtin_memcpy(&ua, &a, 4); __builtin_memcpy(&ub, &b, 4);
  return __builtin_amdgcn_perm(ua, ub, 0x07060302u);
}

#define GLL(gp, lp) __builtin_amdgcn_global_load_lds( \
    (const __attribute__((address_space(1))) void*)(gp), \
    (__attribute__((address_space(3))) void*)(lp), 16, 0, 0)

__device__ __forceinline__ int swz(int r) { return (r + (r >> 2)) & 3; }

// ---------------------------------------------------------------------------
// All weight transposes in one launch. grid (16,16,24): z -> which(6) x l(4).
// out[l][n][k] = bf16(in[l][k][n]).
// ---------------------------------------------------------------------------
__global__ __launch_bounds__(256) void tr_all_k(
    const float* __restrict__ Wq, const float* __restrict__ Wk,
    const float* __restrict__ Wv, const float* __restrict__ Wo,
    const float* __restrict__ W1, const float* __restrict__ W2,
    u16* __restrict__ wtqkv, u16* __restrict__ wto,
    u16* __restrict__ wt1, u16* __restrict__ wt2) {
  __shared__ float t[32][33];
  int tx = threadIdx.x, ty = threadIdx.y;
  int z = blockIdx.z, which = z >> 2, l = z & 3;
  const float* in;
  u16* out;
  switch (which) {
    case 0: in = Wq; out = wtqkv + l * 786432; break;
    case 1: in = Wk; out = wtqkv + l * 786432 + 262144; break;
    case 2: in = Wv; out = wtqkv + l * 786432 + 524288; break;
    case 3: in = Wo; out = wto + l * 262144; break;
    case 4: in = W1; out = wt1 + l * 262144; break;
    default: in = W2; out = wt2 + l * 262144; break;
  }
  int k0 = blockIdx.y * 32, n0 = blockIdx.x * 32;
  const float* ip = in + l * 262144;
#pragma unroll
  for (int i = 0; i < 4; i++)
    t[ty + i * 8][tx] = ip[(k0 + ty + i * 8) * 512 + n0 + tx];
  __syncthreads();
#pragma unroll
  for (int i = 0; i < 4; i++)
    out[(n0 + ty + i * 8) * 512 + k0 + tx] = f2b(t[tx][ty + i * 8]);
}

// ---------------------------------------------------------------------------
// LayerNorm: one wave per token (D=512, 8 elems/lane), fp32 in, bf16 out
// ---------------------------------------------------------------------------
__global__ __launch_bounds__(256) void ln_k(const float* __restrict__ h,
                                            const float* __restrict__ gg,
                                            const float* __restrict__ bb,
                                            u16* __restrict__ y) {
  int tid = threadIdx.x, wave = tid >> 6, lane = tid & 63;
  int tok = blockIdx.x * 4 + wave;
  const float* hp = h + (size_t)tok * 512 + lane * 8;
  float x[8];
  *(float4*)&x[0] = *(const float4*)hp;
  *(float4*)&x[4] = *(const float4*)(hp + 4);
  float s = 0.f, ss = 0.f;
#pragma unroll
  for (int i = 0; i < 8; i++) { s += x[i]; ss += x[i] * x[i]; }
#pragma unroll
  for (int off = 1; off < 64; off <<= 1) {
    s += __shfl_xor(s, off, 64);
    ss += __shfl_xor(ss, off, 64);
  }
  float mean = s * (1.0f / 512.0f);
  float var = ss * (1.0f / 512.0f) - mean * mean;
  float rstd = rsqrtf(var + 1e-5f);
  u32x4 ov;
#pragma unroll
  for (int i = 0; i < 4; i++) {
    int d0 = lane * 8 + i * 2;
    float y0 = (x[i * 2]     - mean) * rstd * gg[d0]     + bb[d0];
    float y1 = (x[i * 2 + 1] - mean) * rstd * gg[d0 + 1] + bb[d0 + 1];
    ov[i] = (unsigned)f2b(y0) | ((unsigned)f2b(y1) << 16);
  }
  *(u32x4*)&y[(size_t)tok * 512 + lane * 8] = ov;
}

// ---------------------------------------------------------------------------
// GEMM2: 64x128 tile, BK=64, double-buffered. C[8192][512] = A * Bt^T.
// grid (128 m, 4 n) -> linear = n*128+m -> XCD = m%8 (n-blocks of an
// m-panel share an XCD: A fetched once per XCD). 512 blocks = 2/CU,
// 48 KB LDS. Epilogues: RES (hout = hin + gemm + bias, optional fp32
// fout copy), GELU -> bf16.
// ---------------------------------------------------------------------------
enum { EPI_RES = 1, EPI_GELU = 2 };

template <int EPI>
__global__ __launch_bounds__(256, 2) void gemm2_k(
    const u16* __restrict__ A, const u16* __restrict__ Bt,
    const float* __restrict__ bias, u16* __restrict__ out0,
    const float* __restrict__ hin, float* __restrict__ hout,
    float* __restrict__ fout) {
  __shared__ __align__(16) u16 As[2][64 * 64];   // 2 x 8 KB
  __shared__ __align__(16) u16 Bs[2][128 * 64];  // 2 x 16 KB
  const int tid = threadIdx.x;
  const int wave = tid >> 6, lane = tid & 63;
  const int quad = lane >> 4, l16 = lane & 15;
  const int swl = l16 & 7;
  const int wm = wave >> 1, wn = wave & 1;
  const int m0 = blockIdx.x * 64;
  const int n0 = blockIdx.y * 128;

  f32x4 acc[2][4];
#pragma unroll
  for (int i = 0; i < 2; i++)
#pragma unroll
    for (int j = 0; j < 4; j++) acc[i][j] = f32x4{0.f, 0.f, 0.f, 0.f};

  const int srow = lane >> 3, sgc = (lane & 7) ^ srow;
  int kbA[2], kbB[2];
#pragma unroll
  for (int kk = 0; kk < 2; ++kk) {
    kbA[kk] = (wm * 32 + l16) * 64 + ((kk * 4 + quad) ^ swl) * 8;
    kbB[kk] = (wn * 64 + l16) * 64 + ((kk * 4 + quad) ^ swl) * 8;
  }

  // prologue: stage kt=0 into buf 0 (A: 2 rounds of 32 rows; B: 4 rounds)
#pragma unroll
  for (int rnd = 0; rnd < 2; ++rnd) {
    int row = rnd * 32 + wave * 8 + srow;
    GLL(A + (size_t)(m0 + row) * 512 + sgc * 8, &As[0][(rnd * 32 + wave * 8) * 64]);
  }
#pragma unroll
  for (int rnd = 0; rnd < 4; ++rnd) {
    int row = rnd * 32 + wave * 8 + srow;
    GLL(Bt + (size_t)(n0 + row) * 512 + sgc * 8, &Bs[0][(rnd * 32 + wave * 8) * 64]);
  }

#pragma unroll 2
  for (int kt = 0; kt < 8; ++kt) {
    __syncthreads();
    const u16* AsB = As[kt & 1];
    const u16* BsB = Bs[kt & 1];
    if (kt + 1 < 8) {
      u16* AsN = (u16*)As[(kt & 1) ^ 1];
      u16* BsN = (u16*)Bs[(kt & 1) ^ 1];
      const int k1 = (kt + 1) * 64;
#pragma unroll
      for (int rnd = 0; rnd < 2; ++rnd) {
        int row = rnd * 32 + wave * 8 + srow;
        GLL(A + (size_t)(m0 + row) * 512 + k1 + sgc * 8, AsN + (rnd * 32 + wave * 8) * 64);
      }
#pragma unroll
      for (int rnd = 0; rnd < 4; ++rnd) {
        int row = rnd * 32 + wave * 8 + srow;
        GLL(Bt + (size_t)(n0 + row) * 512 + k1 + sgc * 8, BsN + (rnd * 32 + wave * 8) * 64);
      }
    }

#pragma unroll
    for (int kk = 0; kk < 2; ++kk) {
      bf16x8 af[2], bf_[4];
#pragma unroll
      for (int mi = 0; mi < 2; ++mi) af[mi] = ld8(AsB + kbA[kk] + mi * 1024);
#pragma unroll
      for (int ni = 0; ni < 4; ++ni) bf_[ni] = ld8(BsB + kbB[kk] + ni * 1024);
#pragma unroll
      for (int mi = 0; mi < 2; ++mi)
#pragma unroll
        for (int ni = 0; ni < 4; ++ni)
          acc[mi][ni] = __builtin_amdgcn_mfma_f32_16x16x32_bf16(
              af[mi], bf_[ni], acc[mi][ni], 0, 0, 0);
    }
  }

  // Epilogue. C layout: row = quad*4+reg, col = l16.
  const int mb = m0 + wm * 32, nb = n0 + wn * 64;
#pragma unroll
  for (int mi = 0; mi < 2; ++mi) {
#pragma unroll
    for (int ni = 0; ni < 4; ++ni) {
      f32x4 a = acc[mi][ni];
      int r0 = mb + mi * 16 + quad * 4;
      int c = nb + ni * 16 + l16;
      if constexpr (EPI == EPI_RES) {
        float bi = bias[c];
#pragma unroll
        for (int g = 0; g < 4; ++g) {
          float v = hin[(size_t)(r0 + g) * 512 + c] + a[g] + bi;
          hout[(size_t)(r0 + g) * 512 + c] = v;
          if (fout) fout[(size_t)(r0 + g) * 512 + c] = v;
        }
      } else {  // GELU
        float bi = bias[c];
#pragma unroll
        for (int g = 0; g < 4; ++g) {
          float t = a[g] + bi;
          float gl = 0.5f * t * (1.0f + erff(t * 0.70710678118654752f));
          out0[(size_t)(r0 + g) * 512 + c] = f2b(gl);
        }
      }
    }
  }
}

// ---------------------------------------------------------------------------
// QKV GEMM 128x128 (BK=32): C[8192][1536] = A * Wqkv^T.
// grid (64 m, 12 n) -> XCD = m%8 (A-panel pinned per XCD).
// Epilogue splits Q (pre-scaled by 512^-0.5*log2e), K, V^T.
// ---------------------------------------------------------------------------
__global__ __launch_bounds__(256, 4) void gemm_qkv_k(
    const u16* __restrict__ A, const u16* __restrict__ Bt,
    u16* __restrict__ outq, u16* __restrict__ outk, u16* __restrict__ outvt) {
  __shared__ __align__(16) u16 As[128 * 32];
  __shared__ __align__(16) u16 Bs[128 * 32];
  const int tid = threadIdx.x;
  const int wave = tid >> 6, lane = tid & 63;
  const int quad = lane >> 4, l16 = lane & 15;
  const int wm = wave >> 1, wn = wave & 1;
  const int m0 = blockIdx.x * 128;
  const int n0 = blockIdx.y * 128;

  f32x4 acc[4][4];
#pragma unroll
  for (int i = 0; i < 4; i++)
#pragma unroll
    for (int j = 0; j < 4; j++) acc[i][j] = f32x4{0.f, 0.f, 0.f, 0.f};

  const int sA0 = wave * 64 + lane;

  for (int kt = 0; kt < 16; ++kt) {
    const int k0 = kt * 32;
    __syncthreads();
#pragma unroll
    for (int rnd = 0; rnd < 2; ++rnd) {
      int s = rnd * 256 + sA0;
      int row = s >> 2, c = s & 3;
      int cg = c ^ swz(row);
      GLL(A + (size_t)(m0 + row) * 512 + k0 + cg * 8, &As[(rnd * 256 + wave * 64) * 8]);
      GLL(Bt + (size_t)(n0 + row) * 512 + k0 + cg * 8, &Bs[(rnd * 256 + wave * 64) * 8]);
    }
    __syncthreads();

    bf16x8 af[4], bf_[4];
#pragma unroll
    for (int mi = 0; mi < 4; ++mi) {
      int r = wm * 64 + mi * 16 + l16;
      af[mi] = ld8(&As[r * 32 + (quad ^ swz(r)) * 8]);
    }
#pragma unroll
    for (int ni = 0; ni < 4; ++ni) {
      int r = wn * 64 + ni * 16 + l16;
      bf_[ni] = ld8(&Bs[r * 32 + (quad ^ swz(r)) * 8]);
    }
#pragma unroll
    for (int mi = 0; mi < 4; ++mi)
#pragma unroll
      for (int ni = 0; ni < 4; ++ni)
        acc[mi][ni] = __builtin_amdgcn_mfma_f32_16x16x32_bf16(
            af[mi], bf_[ni], acc[mi][ni], 0, 0, 0);
  }

  const int mb = m0 + wm * 64, nb = n0 + wn * 64;
#pragma unroll
  for (int mi = 0; mi < 4; ++mi) {
#pragma unroll
    for (int ni = 0; ni < 4; ++ni) {
      f32x4 a = acc[mi][ni];
      int r0 = mb + mi * 16 + quad * 4;
      int c = nb + ni * 16 + l16;
      if (c < 512) {
        const float C2 = 0.06375871506958306f;  // 512^-0.5 * log2(e)
#pragma unroll
        for (int g = 0; g < 4; ++g) outq[(size_t)(r0 + g) * 512 + c] = f2b(a[g] * C2);
      } else if (c < 1024) {
#pragma unroll
        for (int g = 0; g < 4; ++g) outk[(size_t)(r0 + g) * 512 + (c - 512)] = f2b(a[g]);
      } else {
        int cv = c - 1024, hh = cv >> 6, dd = cv & 63;
        int bb = r0 >> 11, nt = r0 & 2047;
        u32x2 pk;
        pk[0] = (unsigned)f2b(a[0]) | ((unsigned)f2b(a[1]) << 16);
        pk[1] = (unsigned)f2b(a[2]) | ((unsigned)f2b(a[3]) << 16);
        *(u32x2*)&outvt[((size_t)(bb * 8 + hh) * 64 + dd) * 2048 + nt] = pk;
      }
    }
  }
}

// ---------------------------------------------------------------------------
// Flash attention v5 (2x2 split). grid (32 bh, 32 qt) -> XCD = bh%8:
// each XCD serves 4 heads (2 MB K/V resident in its L2).
// ---------------------------------------------------------------------------
__global__ __launch_bounds__(256, 4) void attn_k(const u16* __restrict__ q,
                                                 const u16* __restrict__ k,
                                                 const u16* __restrict__ vt,
                                                 u16* __restrict__ o) {
  __shared__ __align__(16) u16 Ks[2][64 * 64];   // 16 KB
  __shared__ __align__(16) u16 Vs[2][64 * 64];   // 16 KB
  __shared__ float Lr[4][32];                    // 512 B
  const int tid = threadIdx.x, wave = tid >> 6, lane = tid & 63;
  const int quad = lane >> 4, l16 = lane & 15;
  const int qh = quad >> 1, ql = quad & 1;
  const int swl = l16 & 7;
  const int qh2 = wave & 1, kvs = wave >> 1;
  const int bh = blockIdx.x, b = bh >> 3, h = bh & 7;
  const int qt0 = blockIdx.y * 64;

  const u16* qpb = q + (size_t)(b * 2048 + qt0 + qh2 * 32) * 512 + h * 64;
  bf16x8 aq[2][2];
#pragma unroll
  for (int qt = 0; qt < 2; ++qt) {
    const u16* qp = qpb + (size_t)(qt * 16 + l16) * 512;
    aq[qt][0] = ld8(qp + quad * 8);
    aq[qt][1] = ld8(qp + 32 + quad * 8);
  }

  const u16* kp = k + (size_t)b * 2048 * 512 + h * 64;
  const u16* vp = vt + (size_t)bh * 64 * 2048;

  const int srow = lane >> 3, schk = lane & 7, sgc = schk ^ srow;
  const int krow0 = wave * 8 + srow;
  const size_t kgl0 = (size_t)krow0 * 512 + sgc * 8;
  const size_t kgl1 = (size_t)(krow0 + 32) * 512 + sgc * 8;
  const size_t vgl0 = (size_t)krow0 * 2048 + sgc * 8;
  const size_t vgl1 = (size_t)(krow0 + 32) * 2048 + sgc * 8;

  int kb[2][2];
#pragma unroll
  for (int t = 0; t < 2; ++t) {
    kb[t][0] = (kvs * 32 + t * 16 + l16) * 64 + ((quad)     ^ swl) * 8;
    kb[t][1] = (kvs * 32 + t * 16 + l16) * 64 + ((4 + quad) ^ swl) * 8;
  }
  int vb[2];
#pragma unroll
  for (int t = 0; t < 2; ++t)
    vb[t] = l16 * 64 + ((kvs * 4 + t * 2 + qh) ^ swl) * 8 + ql * 4;

  f32x4 oacc[4][2];
#pragma unroll
  for (int i = 0; i < 4; i++)
#pragma unroll
    for (int j = 0; j < 2; j++) oacc[i][j] = f32x4{0.f, 0.f, 0.f, 0.f};
  float ls[2] = {0.f, 0.f};

  GLL(kp + kgl0, &Ks[0][(wave * 8) * 64]);
  GLL(kp + kgl1, &Ks[0][(32 + wave * 8) * 64]);
  GLL(vp + vgl0, &Vs[0][(wave * 8) * 64]);
  GLL(vp + vgl1, &Vs[0][(32 + wave * 8) * 64]);

#pragma unroll 2
  for (int kt = 0; kt < 32; ++kt) {
    __syncthreads();
    const u16* KsB = Ks[kt & 1];
    const u16* VsB = Vs[kt & 1];
    if (kt + 1 < 32) {
      u16* KsN = (u16*)Ks[(kt & 1) ^ 1];
      u16* VsN = (u16*)Vs[(kt & 1) ^ 1];
      const u16* kpn = kp + (size_t)(kt + 1) * 32768;
      const u16* vpn = vp + (size_t)(kt + 1) * 64;
      GLL(kpn + kgl0, KsN + (wave * 8) * 64);
      GLL(kpn + kgl1, KsN + (32 + wave * 8) * 64);
      GLL(vpn + vgl0, VsN + (wave * 8) * 64);
      GLL(vpn + vgl1, VsN + (32 + wave * 8) * 64);
    }

    short4v pp[2][2];
#pragma unroll
    for (int t = 0; t < 2; ++t) {
      bf16x8 kf0 = ld8(KsB + kb[t][0]);
      bf16x8 kf1 = ld8(KsB + kb[t][1]);
#pragma unroll
      for (int qt = 0; qt < 2; ++qt) {
        f32x4 sa = f32x4{0.f, 0.f, 0.f, 0.f};
        sa = __builtin_amdgcn_mfma_f32_16x16x32_bf16(kf0, aq[qt][0], sa, 0, 0, 0);
        sa = __builtin_amdgcn_mfma_f32_16x16x32_bf16(kf1, aq[qt][1], sa, 0, 0, 0);
        float p0 = __builtin_amdgcn_exp2f(sa[0]);
        float p1 = __builtin_amdgcn_exp2f(sa[1]);
        float p2 = __builtin_amdgcn_exp2f(sa[2]);
        float p3 = __builtin_amdgcn_exp2f(sa[3]);
        ls[qt] += (p0 + p1) + (p2 + p3);
        u32x2 pk; pk[0] = pkhi(p1, p0); pk[1] = pkhi(p3, p2);
        __builtin_memcpy(&pp[t][qt], &pk, 8);
      }
    }

#pragma unroll
    for (int dt = 0; dt < 4; ++dt)
#pragma unroll
      for (int t = 0; t < 2; ++t) {
        short4v av = ld4(VsB + vb[t] + dt * 1024);
#pragma unroll
        for (int qt = 0; qt < 2; ++qt)
          oacc[dt][qt] = __builtin_amdgcn_mfma_f32_16x16x16bf16_1k(
              av, pp[t][qt], oacc[dt][qt], 0, 0, 0);
      }
  }

#pragma unroll
  for (int qt = 0; qt < 2; ++qt) {
    ls[qt] += __shfl_xor(ls[qt], 16, 64);
    ls[qt] += __shfl_xor(ls[qt], 32, 64);
  }
  if (quad == 0) {
#pragma unroll
    for (int qt = 0; qt < 2; ++qt) Lr[wave][qt * 16 + l16] = ls[qt];
  }
  __syncthreads();

  float* R = (float*)&Ks[0][0];
  const int l7 = lane & 7;
  if (wave >= 2) {
    float* Rw = R + (wave - 2) * 2048;
#pragma unroll
    for (int dt = 0; dt < 4; ++dt)
#pragma unroll
      for (int qt = 0; qt < 2; ++qt) {
        int s = (dt * 2 + qt) ^ l7;
        *(f32x4*)&Rw[lane * 32 + s * 4] = oacc[dt][qt];
      }
  }
  __syncthreads();
  if (wave < 2) {
    float* Rw = R + wave * 2048;
    float inv[2];
#pragma unroll
    for (int qt = 0; qt < 2; ++qt)
      inv[qt] = 1.0f / (Lr[wave][qt * 16 + l16] + Lr[wave + 2][qt * 16 + l16]);
#pragma unroll
    for (int dt = 0; dt < 4; ++dt)
#pragma unroll
      for (int qt = 0; qt < 2; ++qt) {
        int s = (dt * 2 + qt) ^ l7;
        f32x4 v = *(f32x4*)&Rw[lane * 32 + s * 4];
        float i4 = inv[qt];
        float o0 = (oacc[dt][qt][0] + v[0]) * i4;
        float o1 = (oacc[dt][qt][1] + v[1]) * i4;
        float o2 = (oacc[dt][qt][2] + v[2]) * i4;
        float o3 = (oacc[dt][qt][3] + v[3]) * i4;
        u16* op = o + (size_t)(b * 2048 + qt0 + wave * 32 + qt * 16 + l16) * 512 +
                  h * 64 + dt * 16 + quad * 4;
        u32x2 pk;
        pk[0] = (unsigned)f2b(o0) | ((unsigned)f2b(o1) << 16);
        pk[1] = (unsigned)f2b(o2) | ((unsigned)f2b(o3) << 16);
        *(u32x2*)op = pk;
      }
  }
}

// ---------------------------------------------------------------------------
extern "C" void kernel_launch(void* const* d_in, const int* in_sizes, int n_in,
                              void* d_out, int out_size, void* d_ws,
                              size_t ws_size, hipStream_t stream) {
  const float* x   = (const float*)d_in[0];
  const float* Wq  = (const float*)d_in[1];
  const float* Wk  = (const float*)d_in[2];
  const float* Wv  = (const float*)d_in[3];
  const float* Wo  = (const float*)d_in[4];
  const float* bo  = (const float*)d_in[5];
  const float* g1  = (const float*)d_in[6];
  const float* bg1 = (const float*)d_in[7];
  const float* W1  = (const float*)d_in[8];
  const float* b1  = (const float*)d_in[9];
  const float* W2  = (const float*)d_in[10];
  const float* b2  = (const float*)d_in[11];
  const float* g2  = (const float*)d_in[12];
  const float* bg2 = (const float*)d_in[13];

  char* ws = (char*)d_ws;
  float* h    = (float*)ws;                        // 16 MB fp32 residual
  u16* yb     = (u16*)(ws + (16ll << 20));         // 8 MB LN output (bf16)
  u16* qb     = (u16*)(ws + (24ll << 20));         // 8 MB q / ffn-intermediate
  u16* kb     = (u16*)(ws + (32ll << 20));         // 8 MB k
  u16* vtb    = (u16*)(ws + (40ll << 20));         // 8 MB v transposed [b,h,d,n]
  u16* ob     = (u16*)(ws + (48ll << 20));         // 8 MB attn out
  u16* wtqkv  = (u16*)(ws + (56ll << 20));         // 6 MB [l][1536][512] bf16
  u16* wto    = (u16*)(ws + (62ll << 20));         // 2 MB
  u16* wt1    = (u16*)(ws + (64ll << 20));         // 2 MB
  u16* wt2    = (u16*)(ws + (66ll << 20));         // 2 MB  (total 68 MB)

  tr_all_k<<<dim3(16, 16, 24), dim3(32, 8), 0, stream>>>(
      Wq, Wk, Wv, Wo, W1, W2, wtqkv, wto, wt1, wt2);

  for (int l = 0; l < 4; ++l) {
    const float* hsrc = (l == 0) ? x : h;
    ln_k<<<2048, 256, 0, stream>>>(hsrc, g1 + l * 512, bg1 + l * 512, yb);
    gemm_qkv_k<<<dim3(64, 12), 256, 0, stream>>>(
        yb, wtqkv + l * 786432, qb, kb, vtb);
    attn_k<<<dim3(32, 32), 256, 0, stream>>>(qb, kb, vtb, ob);
    gemm2_k<EPI_RES><<<dim3(128, 4), 256, 0, stream>>>(
        ob, wto + l * 262144, bo + l * 512, nullptr, hsrc, h, nullptr);
    ln_k<<<2048, 256, 0, stream>>>(h, g2 + l * 512, bg2 + l * 512, yb);
    gemm2_k<EPI_GELU><<<dim3(128, 4), 256, 0, stream>>>(
        yb, wt1 + l * 262144, b1 + l * 512, qb, nullptr, nullptr, nullptr);
    gemm2_k<EPI_RES><<<dim3(128, 4), 256, 0, stream>>>(
        qb, wt2 + l * 262144, b2 + l * 512, nullptr, h, h,
        (l == 3) ? (float*)d_out : nullptr);
  }
}

// Round 9
// 590.254 us; speedup vs baseline: 1.2188x; 1.0536x over previous
//
#include <hip/hip_runtime.h>
#include <hip/hip_bf16.h>

// Problem: L=4 B=4 N=2048 D=512 H=8 HD=64. Inputs/outputs FP32.
// Weights transposed+cast to bf16 once; bf16 MFMA, fp32 accumulate; fp32
// residual stream. scale = 512^-0.5 (D**-0.5 per ref).
// Round 9: gemm2 -> BK=32 dbuf (24 KB LDS, 4 blocks/CU) + hin residual
// tile preloaded to VGPRs at kernel start (epilogue latency hidden).
// XCD-pinned grids and attention v5 unchanged from round 8.

typedef __bf16 bf16x8 __attribute__((ext_vector_type(8)));
typedef short short4v __attribute__((ext_vector_type(4)));
typedef float f32x4 __attribute__((ext_vector_type(4)));
typedef unsigned int u32x4 __attribute__((ext_vector_type(4)));
typedef unsigned int u32x2 __attribute__((ext_vector_type(2)));
typedef unsigned short u16;

__device__ __forceinline__ u16 f2b(float f) {  // RNE (values are finite)
  unsigned int u; __builtin_memcpy(&u, &f, 4);
  u += 0x7fffu + ((u >> 16) & 1u);
  return (u16)(u >> 16);
}
__device__ __forceinline__ bf16x8 ld8(const u16* p) {
  u32x4 t = *(const u32x4*)p;
  bf16x8 r; __builtin_memcpy(&r, &t, 16); return r;
}
__device__ __forceinline__ short4v ld4(const u16* p) {
  u32x2 t = *(const u32x2*)p;
  short4v r; __builtin_memcpy(&r, &t, 8); return r;
}
__device__ __forceinline__ unsigned pkhi(float a, float b) {
  unsigned ua, ub; __builtin_memcpy(&ua, &a, 4); __builtin_memcpy(&ub, &b, 4);
  return __builtin_amdgcn_perm(ua, ub, 0x07060302u);
}

#define GLL(gp, lp) __builtin_amdgcn_global_load_lds( \
    (const __attribute__((address_space(1))) void*)(gp), \
    (__attribute__((address_space(3))) void*)(lp), 16, 0, 0)

__device__ __forceinline__ int swz(int r) { return (r + (r >> 2)) & 3; }

// ---------------------------------------------------------------------------
// All weight transposes in one launch. grid (16,16,24): z -> which(6) x l(4).
// out[l][n][k] = bf16(in[l][k][n]).
// ---------------------------------------------------------------------------
__global__ __launch_bounds__(256) void tr_all_k(
    const float* __restrict__ Wq, const float* __restrict__ Wk,
    const float* __restrict__ Wv, const float* __restrict__ Wo,
    const float* __restrict__ W1, const float* __restrict__ W2,
    u16* __restrict__ wtqkv, u16* __restrict__ wto,
    u16* __restrict__ wt1, u16* __restrict__ wt2) {
  __shared__ float t[32][33];
  int tx = threadIdx.x, ty = threadIdx.y;
  int z = blockIdx.z, which = z >> 2, l = z & 3;
  const float* in;
  u16* out;
  switch (which) {
    case 0: in = Wq; out = wtqkv + l * 786432; break;
    case 1: in = Wk; out = wtqkv + l * 786432 + 262144; break;
    case 2: in = Wv; out = wtqkv + l * 786432 + 524288; break;
    case 3: in = Wo; out = wto + l * 262144; break;
    case 4: in = W1; out = wt1 + l * 262144; break;
    default: in = W2; out = wt2 + l * 262144; break;
  }
  int k0 = blockIdx.y * 32, n0 = blockIdx.x * 32;
  const float* ip = in + l * 262144;
#pragma unroll
  for (int i = 0; i < 4; i++)
    t[ty + i * 8][tx] = ip[(k0 + ty + i * 8) * 512 + n0 + tx];
  __syncthreads();
#pragma unroll
  for (int i = 0; i < 4; i++)
    out[(n0 + ty + i * 8) * 512 + k0 + tx] = f2b(t[tx][ty + i * 8]);
}

// ---------------------------------------------------------------------------
// LayerNorm: one wave per token (D=512, 8 elems/lane), fp32 in, bf16 out
// ---------------------------------------------------------------------------
__global__ __launch_bounds__(256) void ln_k(const float* __restrict__ h,
                                            const float* __restrict__ gg,
                                            const float* __restrict__ bb,
                                            u16* __restrict__ y) {
  int tid = threadIdx.x, wave = tid >> 6, lane = tid & 63;
  int tok = blockIdx.x * 4 + wave;
  const float* hp = h + (size_t)tok * 512 + lane * 8;
  float x[8];
  *(float4*)&x[0] = *(const float4*)hp;
  *(float4*)&x[4] = *(const float4*)(hp + 4);
  float s = 0.f, ss = 0.f;
#pragma unroll
  for (int i = 0; i < 8; i++) { s += x[i]; ss += x[i] * x[i]; }
#pragma unroll
  for (int off = 1; off < 64; off <<= 1) {
    s += __shfl_xor(s, off, 64);
    ss += __shfl_xor(ss, off, 64);
  }
  float mean = s * (1.0f / 512.0f);
  float var = ss * (1.0f / 512.0f) - mean * mean;
  float rstd = rsqrtf(var + 1e-5f);
  u32x4 ov;
#pragma unroll
  for (int i = 0; i < 4; i++) {
    int d0 = lane * 8 + i * 2;
    float y0 = (x[i * 2]     - mean) * rstd * gg[d0]     + bb[d0];
    float y1 = (x[i * 2 + 1] - mean) * rstd * gg[d0 + 1] + bb[d0 + 1];
    ov[i] = (unsigned)f2b(y0) | ((unsigned)f2b(y1) << 16);
  }
  *(u32x4*)&y[(size_t)tok * 512 + lane * 8] = ov;
}

// ---------------------------------------------------------------------------
// GEMM2 v2: 64x128 tile, BK=32, double-buffered, 24 KB LDS -> 4 blocks/CU.
// grid (128 m, 4 n) -> XCD = m%8. RES preloads the 64x128 hin tile into
// 32 VGPRs before the main loop (latency hidden); epilogue = FMA + store.
// ---------------------------------------------------------------------------
enum { EPI_RES = 1, EPI_GELU = 2 };

template <int EPI>
__global__ __launch_bounds__(256, 4) void gemm2_k(
    const u16* __restrict__ A, const u16* __restrict__ Bt,
    const float* __restrict__ bias, u16* __restrict__ out0,
    const float* __restrict__ hin, float* __restrict__ hout,
    float* __restrict__ fout) {
  __shared__ __align__(16) u16 As[2][64 * 32];   // 2 x 4 KB
  __shared__ __align__(16) u16 Bs[2][128 * 32];  // 2 x 8 KB
  const int tid = threadIdx.x;
  const int wave = tid >> 6, lane = tid & 63;
  const int quad = lane >> 4, l16 = lane & 15;
  const int wm = wave >> 1, wn = wave & 1;
  const int m0 = blockIdx.x * 64;
  const int n0 = blockIdx.y * 128;
  const int mb = m0 + wm * 32, nb = n0 + wn * 64;

  // hin residual tile -> regs (RES only); completes during the main loop
  float hr[2][4][4];
  if constexpr (EPI == EPI_RES) {
#pragma unroll
    for (int mi = 0; mi < 2; ++mi)
#pragma unroll
      for (int ni = 0; ni < 4; ++ni) {
        int r0 = mb + mi * 16 + quad * 4, c = nb + ni * 16 + l16;
#pragma unroll
        for (int g = 0; g < 4; ++g)
          hr[mi][ni][g] = hin[(size_t)(r0 + g) * 512 + c];
      }
  }

  f32x4 acc[2][4];
#pragma unroll
  for (int i = 0; i < 2; i++)
#pragma unroll
    for (int j = 0; j < 4; j++) acc[i][j] = f32x4{0.f, 0.f, 0.f, 0.f};

  const int sA0 = wave * 64 + lane;
  // A: 64 rows x 4 chunks = 256 segs (1 round); B: 128 x 4 = 512 (2 rounds)
  const int rowA = sA0 >> 2, cgA = (sA0 & 3) ^ swz(rowA);
  const size_t agl = (size_t)(m0 + rowA) * 512 + cgA * 8;
  int rowB[2], cgB[2];
#pragma unroll
  for (int rnd = 0; rnd < 2; ++rnd) {
    int s = rnd * 256 + sA0;
    rowB[rnd] = s >> 2;
    cgB[rnd] = (s & 3) ^ swz(rowB[rnd]);
  }
  const size_t bgl0 = (size_t)(n0 + rowB[0]) * 512 + cgB[0] * 8;
  const size_t bgl1 = (size_t)(n0 + rowB[1]) * 512 + cgB[1] * 8;

  // frag bases (kt-invariant)
  int kbA[2], kbB[4];
#pragma unroll
  for (int mi = 0; mi < 2; ++mi) {
    int r = wm * 32 + mi * 16 + l16;
    kbA[mi] = r * 32 + (quad ^ swz(r)) * 8;
  }
#pragma unroll
  for (int ni = 0; ni < 4; ++ni) {
    int r = wn * 64 + ni * 16 + l16;
    kbB[ni] = r * 32 + (quad ^ swz(r)) * 8;
  }

  // prologue: stage kt=0 into buf 0
  GLL(A + agl, &As[0][(wave * 64) * 8]);
  GLL(Bt + bgl0, &Bs[0][(wave * 64) * 8]);
  GLL(Bt + bgl1, &Bs[0][(256 + wave * 64) * 8]);

#pragma unroll 2
  for (int kt = 0; kt < 16; ++kt) {
    __syncthreads();
    const u16* AsB = As[kt & 1];
    const u16* BsB = Bs[kt & 1];
    if (kt + 1 < 16) {
      u16* AsN = (u16*)As[(kt & 1) ^ 1];
      u16* BsN = (u16*)Bs[(kt & 1) ^ 1];
      const int k1 = (kt + 1) * 32;
      GLL(A + agl + k1, AsN + (wave * 64) * 8);
      GLL(Bt + bgl0 + k1, BsN + (wave * 64) * 8);
      GLL(Bt + bgl1 + k1, BsN + (256 + wave * 64) * 8);
    }

    bf16x8 af[2], bf_[4];
#pragma unroll
    for (int mi = 0; mi < 2; ++mi) af[mi] = ld8(AsB + kbA[mi]);
#pragma unroll
    for (int ni = 0; ni < 4; ++ni) bf_[ni] = ld8(BsB + kbB[ni]);
#pragma unroll
    for (int mi = 0; mi < 2; ++mi)
#pragma unroll
      for (int ni = 0; ni < 4; ++ni)
        acc[mi][ni] = __builtin_amdgcn_mfma_f32_16x16x32_bf16(
            af[mi], bf_[ni], acc[mi][ni], 0, 0, 0);
  }

  // Epilogue. C layout: row = quad*4+reg, col = l16.
#pragma unroll
  for (int mi = 0; mi < 2; ++mi) {
#pragma unroll
    for (int ni = 0; ni < 4; ++ni) {
      f32x4 a = acc[mi][ni];
      int r0 = mb + mi * 16 + quad * 4;
      int c = nb + ni * 16 + l16;
      float bi = bias[c];
      if constexpr (EPI == EPI_RES) {
#pragma unroll
        for (int g = 0; g < 4; ++g) {
          float v = hr[mi][ni][g] + a[g] + bi;
          hout[(size_t)(r0 + g) * 512 + c] = v;
          if (fout) fout[(size_t)(r0 + g) * 512 + c] = v;
        }
      } else {  // GELU
#pragma unroll
        for (int g = 0; g < 4; ++g) {
          float t = a[g] + bi;
          float gl = 0.5f * t * (1.0f + erff(t * 0.70710678118654752f));
          out0[(size_t)(r0 + g) * 512 + c] = f2b(gl);
        }
      }
    }
  }
}

// ---------------------------------------------------------------------------
// QKV GEMM 128x128 (BK=32): C[8192][1536] = A * Wqkv^T.
// grid (64 m, 12 n) -> XCD = m%8 (A-panel pinned per XCD).
// Epilogue splits Q (pre-scaled by 512^-0.5*log2e), K, V^T.
// ---------------------------------------------------------------------------
__global__ __launch_bounds__(256, 4) void gemm_qkv_k(
    const u16* __restrict__ A, const u16* __restrict__ Bt,
    u16* __restrict__ outq, u16* __restrict__ outk, u16* __restrict__ outvt) {
  __shared__ __align__(16) u16 As[128 * 32];
  __shared__ __align__(16) u16 Bs[128 * 32];
  const int tid = threadIdx.x;
  const int wave = tid >> 6, lane = tid & 63;
  const int quad = lane >> 4, l16 = lane & 15;
  const int wm = wave >> 1, wn = wave & 1;
  const int m0 = blockIdx.x * 128;
  const int n0 = blockIdx.y * 128;

  f32x4 acc[4][4];
#pragma unroll
  for (int i = 0; i < 4; i++)
#pragma unroll
    for (int j = 0; j < 4; j++) acc[i][j] = f32x4{0.f, 0.f, 0.f, 0.f};

  const int sA0 = wave * 64 + lane;

  for (int kt = 0; kt < 16; ++kt) {
    const int k0 = kt * 32;
    __syncthreads();
#pragma unroll
    for (int rnd = 0; rnd < 2; ++rnd) {
      int s = rnd * 256 + sA0;
      int row = s >> 2, c = s & 3;
      int cg = c ^ swz(row);
      GLL(A + (size_t)(m0 + row) * 512 + k0 + cg * 8, &As[(rnd * 256 + wave * 64) * 8]);
      GLL(Bt + (size_t)(n0 + row) * 512 + k0 + cg * 8, &Bs[(rnd * 256 + wave * 64) * 8]);
    }
    __syncthreads();

    bf16x8 af[4], bf_[4];
#pragma unroll
    for (int mi = 0; mi < 4; ++mi) {
      int r = wm * 64 + mi * 16 + l16;
      af[mi] = ld8(&As[r * 32 + (quad ^ swz(r)) * 8]);
    }
#pragma unroll
    for (int ni = 0; ni < 4; ++ni) {
      int r = wn * 64 + ni * 16 + l16;
      bf_[ni] = ld8(&Bs[r * 32 + (quad ^ swz(r)) * 8]);
    }
#pragma unroll
    for (int mi = 0; mi < 4; ++mi)
#pragma unroll
      for (int ni = 0; ni < 4; ++ni)
        acc[mi][ni] = __builtin_amdgcn_mfma_f32_16x16x32_bf16(
            af[mi], bf_[ni], acc[mi][ni], 0, 0, 0);
  }

  const int mb = m0 + wm * 64, nb = n0 + wn * 64;
#pragma unroll
  for (int mi = 0; mi < 4; ++mi) {
#pragma unroll
    for (int ni = 0; ni < 4; ++ni) {
      f32x4 a = acc[mi][ni];
      int r0 = mb + mi * 16 + quad * 4;
      int c = nb + ni * 16 + l16;
      if (c < 512) {
        const float C2 = 0.06375871506958306f;  // 512^-0.5 * log2(e)
#pragma unroll
        for (int g = 0; g < 4; ++g) outq[(size_t)(r0 + g) * 512 + c] = f2b(a[g] * C2);
      } else if (c < 1024) {
#pragma unroll
        for (int g = 0; g < 4; ++g) outk[(size_t)(r0 + g) * 512 + (c - 512)] = f2b(a[g]);
      } else {
        int cv = c - 1024, hh = cv >> 6, dd = cv & 63;
        int bb = r0 >> 11, nt = r0 & 2047;
        u32x2 pk;
        pk[0] = (unsigned)f2b(a[0]) | ((unsigned)f2b(a[1]) << 16);
        pk[1] = (unsigned)f2b(a[2]) | ((unsigned)f2b(a[3]) << 16);
        *(u32x2*)&outvt[((size_t)(bb * 8 + hh) * 64 + dd) * 2048 + nt] = pk;
      }
    }
  }
}

// ---------------------------------------------------------------------------
// Flash attention v5 (2x2 split). grid (32 bh, 32 qt) -> XCD = bh%8.
// ---------------------------------------------------------------------------
__global__ __launch_bounds__(256, 4) void attn_k(const u16* __restrict__ q,
                                                 const u16* __restrict__ k,
                                                 const u16* __restrict__ vt,
                                                 u16* __restrict__ o) {
  __shared__ __align__(16) u16 Ks[2][64 * 64];   // 16 KB
  __shared__ __align__(16) u16 Vs[2][64 * 64];   // 16 KB
  __shared__ float Lr[4][32];                    // 512 B
  const int tid = threadIdx.x, wave = tid >> 6, lane = tid & 63;
  const int quad = lane >> 4, l16 = lane & 15;
  const int qh = quad >> 1, ql = quad & 1;
  const int swl = l16 & 7;
  const int qh2 = wave & 1, kvs = wave >> 1;
  const int bh = blockIdx.x, b = bh >> 3, h = bh & 7;
  const int qt0 = blockIdx.y * 64;

  const u16* qpb = q + (size_t)(b * 2048 + qt0 + qh2 * 32) * 512 + h * 64;
  bf16x8 aq[2][2];
#pragma unroll
  for (int qt = 0; qt < 2; ++qt) {
    const u16* qp = qpb + (size_t)(qt * 16 + l16) * 512;
    aq[qt][0] = ld8(qp + quad * 8);
    aq[qt][1] = ld8(qp + 32 + quad * 8);
  }

  const u16* kp = k + (size_t)b * 2048 * 512 + h * 64;
  const u16* vp = vt + (size_t)bh * 64 * 2048;

  const int srow = lane >> 3, schk = lane & 7, sgc = schk ^ srow;
  const int krow0 = wave * 8 + srow;
  const size_t kgl0 = (size_t)krow0 * 512 + sgc * 8;
  const size_t kgl1 = (size_t)(krow0 + 32) * 512 + sgc * 8;
  const size_t vgl0 = (size_t)krow0 * 2048 + sgc * 8;
  const size_t vgl1 = (size_t)(krow0 + 32) * 2048 + sgc * 8;

  int kb[2][2];
#pragma unroll
  for (int t = 0; t < 2; ++t) {
    kb[t][0] = (kvs * 32 + t * 16 + l16) * 64 + ((quad)     ^ swl) * 8;
    kb[t][1] = (kvs * 32 + t * 16 + l16) * 64 + ((4 + quad) ^ swl) * 8;
  }
  int vb[2];
#pragma unroll
  for (int t = 0; t < 2; ++t)
    vb[t] = l16 * 64 + ((kvs * 4 + t * 2 + qh) ^ swl) * 8 + ql * 4;

  f32x4 oacc[4][2];
#pragma unroll
  for (int i = 0; i < 4; i++)
#pragma unroll
    for (int j = 0; j < 2; j++) oacc[i][j] = f32x4{0.f, 0.f, 0.f, 0.f};
  float ls[2] = {0.f, 0.f};

  GLL(kp + kgl0, &Ks[0][(wave * 8) * 64]);
  GLL(kp + kgl1, &Ks[0][(32 + wave * 8) * 64]);
  GLL(vp + vgl0, &Vs[0][(wave * 8) * 64]);
  GLL(vp + vgl1, &Vs[0][(32 + wave * 8) * 64]);

#pragma unroll 2
  for (int kt = 0; kt < 32; ++kt) {
    __syncthreads();
    const u16* KsB = Ks[kt & 1];
    const u16* VsB = Vs[kt & 1];
    if (kt + 1 < 32) {
      u16* KsN = (u16*)Ks[(kt & 1) ^ 1];
      u16* VsN = (u16*)Vs[(kt & 1) ^ 1];
      const u16* kpn = kp + (size_t)(kt + 1) * 32768;
      const u16* vpn = vp + (size_t)(kt + 1) * 64;
      GLL(kpn + kgl0, KsN + (wave * 8) * 64);
      GLL(kpn + kgl1, KsN + (32 + wave * 8) * 64);
      GLL(vpn + vgl0, VsN + (wave * 8) * 64);
      GLL(vpn + vgl1, VsN + (32 + wave * 8) * 64);
    }

    short4v pp[2][2];
#pragma unroll
    for (int t = 0; t < 2; ++t) {
      bf16x8 kf0 = ld8(KsB + kb[t][0]);
      bf16x8 kf1 = ld8(KsB + kb[t][1]);
#pragma unroll
      for (int qt = 0; qt < 2; ++qt) {
        f32x4 sa = f32x4{0.f, 0.f, 0.f, 0.f};
        sa = __builtin_amdgcn_mfma_f32_16x16x32_bf16(kf0, aq[qt][0], sa, 0, 0, 0);
        sa = __builtin_amdgcn_mfma_f32_16x16x32_bf16(kf1, aq[qt][1], sa, 0, 0, 0);
        float p0 = __builtin_amdgcn_exp2f(sa[0]);
        float p1 = __builtin_amdgcn_exp2f(sa[1]);
        float p2 = __builtin_amdgcn_exp2f(sa[2]);
        float p3 = __builtin_amdgcn_exp2f(sa[3]);
        ls[qt] += (p0 + p1) + (p2 + p3);
        u32x2 pk; pk[0] = pkhi(p1, p0); pk[1] = pkhi(p3, p2);
        __builtin_memcpy(&pp[t][qt], &pk, 8);
      }
    }

#pragma unroll
    for (int dt = 0; dt < 4; ++dt)
#pragma unroll
      for (int t = 0; t < 2; ++t) {
        short4v av = ld4(VsB + vb[t] + dt * 1024);
#pragma unroll
        for (int qt = 0; qt < 2; ++qt)
          oacc[dt][qt] = __builtin_amdgcn_mfma_f32_16x16x16bf16_1k(
              av, pp[t][qt], oacc[dt][qt], 0, 0, 0);
      }
  }

#pragma unroll
  for (int qt = 0; qt < 2; ++qt) {
    ls[qt] += __shfl_xor(ls[qt], 16, 64);
    ls[qt] += __shfl_xor(ls[qt], 32, 64);
  }
  if (quad == 0) {
#pragma unroll
    for (int qt = 0; qt < 2; ++qt) Lr[wave][qt * 16 + l16] = ls[qt];
  }
  __syncthreads();

  float* R = (float*)&Ks[0][0];
  const int l7 = lane & 7;
  if (wave >= 2) {
    float* Rw = R + (wave - 2) * 2048;
#pragma unroll
    for (int dt = 0; dt < 4; ++dt)
#pragma unroll
      for (int qt = 0; qt < 2; ++qt) {
        int s = (dt * 2 + qt) ^ l7;
        *(f32x4*)&Rw[lane * 32 + s * 4] = oacc[dt][qt];
      }
  }
  __syncthreads();
  if (wave < 2) {
    float* Rw = R + wave * 2048;
    float inv[2];
#pragma unroll
    for (int qt = 0; qt < 2; ++qt)
      inv[qt] = 1.0f / (Lr[wave][qt * 16 + l16] + Lr[wave + 2][qt * 16 + l16]);
#pragma unroll
    for (int dt = 0; dt < 4; ++dt)
#pragma unroll
      for (int qt = 0; qt < 2; ++qt) {
        int s = (dt * 2 + qt) ^ l7;
        f32x4 v = *(f32x4*)&Rw[lane * 32 + s * 4];
        float i4 = inv[qt];
        float o0 = (oacc[dt][qt][0] + v[0]) * i4;
        float o1 = (oacc[dt][qt][1] + v[1]) * i4;
        float o2 = (oacc[dt][qt][2] + v[2]) * i4;
        float o3 = (oacc[dt][qt][3] + v[3]) * i4;
        u16* op = o + (size_t)(b * 2048 + qt0 + wave * 32 + qt * 16 + l16) * 512 +
                  h * 64 + dt * 16 + quad * 4;
        u32x2 pk;
        pk[0] = (unsigned)f2b(o0) | ((unsigned)f2b(o1) << 16);
        pk[1] = (unsigned)f2b(o2) | ((unsigned)f2b(o3) << 16);
        *(u32x2*)op = pk;
      }
  }
}

// ---------------------------------------------------------------------------
extern "C" void kernel_launch(void* const* d_in, const int* in_sizes, int n_in,
                              void* d_out, int out_size, void* d_ws,
                              size_t ws_size, hipStream_t stream) {
  const float* x   = (const float*)d_in[0];
  const float* Wq  = (const float*)d_in[1];
  const float* Wk  = (const float*)d_in[2];
  const float* Wv  = (const float*)d_in[3];
  const float* Wo  = (const float*)d_in[4];
  const float* bo  = (const float*)d_in[5];
  const float* g1  = (const float*)d_in[6];
  const float* bg1 = (const float*)d_in[7];
  const float* W1  = (const float*)d_in[8];
  const float* b1  = (const float*)d_in[9];
  const float* W2  = (const float*)d_in[10];
  const float* b2  = (const float*)d_in[11];
  const float* g2  = (const float*)d_in[12];
  const float* bg2 = (const float*)d_in[13];

  char* ws = (char*)d_ws;
  float* h    = (float*)ws;                        // 16 MB fp32 residual
  u16* yb     = (u16*)(ws + (16ll << 20));         // 8 MB LN output (bf16)
  u16* qb     = (u16*)(ws + (24ll << 20));         // 8 MB q / ffn-intermediate
  u16* kb     = (u16*)(ws + (32ll << 20));         // 8 MB k
  u16* vtb    = (u16*)(ws + (40ll << 20));         // 8 MB v transposed [b,h,d,n]
  u16* ob     = (u16*)(ws + (48ll << 20));         // 8 MB attn out
  u16* wtqkv  = (u16*)(ws + (56ll << 20));         // 6 MB [l][1536][512] bf16
  u16* wto    = (u16*)(ws + (62ll << 20));         // 2 MB
  u16* wt1    = (u16*)(ws + (64ll << 20));         // 2 MB
  u16* wt2    = (u16*)(ws + (66ll << 20));         // 2 MB  (total 68 MB)

  tr_all_k<<<dim3(16, 16, 24), dim3(32, 8), 0, stream>>>(
      Wq, Wk, Wv, Wo, W1, W2, wtqkv, wto, wt1, wt2);

  for (int l = 0; l < 4; ++l) {
    const float* hsrc = (l == 0) ? x : h;
    ln_k<<<2048, 256, 0, stream>>>(hsrc, g1 + l * 512, bg1 + l * 512, yb);
    gemm_qkv_k<<<dim3(64, 12), 256, 0, stream>>>(
        yb, wtqkv + l * 786432, qb, kb, vtb);
    attn_k<<<dim3(32, 32), 256, 0, stream>>>(qb, kb, vtb, ob);
    gemm2_k<EPI_RES><<<dim3(128, 4), 256, 0, stream>>>(
        ob, wto + l * 262144, bo + l * 512, nullptr, hsrc, h, nullptr);
    ln_k<<<2048, 256, 0, stream>>>(h, g2 + l * 512, bg2 + l * 512, yb);
    gemm2_k<EPI_GELU><<<dim3(128, 4), 256, 0, stream>>>(
        yb, wt1 + l * 262144, b1 + l * 512, qb, nullptr, nullptr, nullptr);
    gemm2_k<EPI_RES><<<dim3(128, 4), 256, 0, stream>>>(
        qb, wt2 + l * 262144, b2 + l * 512, nullptr, h, h,
        (l == 3) ? (float*)d_out : nullptr);
  }
}